// Round 13
// baseline (3855.429 us; speedup 1.0000x reference)
//
#include <hip/hip_runtime.h>
#include <math.h>

// Problem constants
#define NB   16
#define CC   256
#define NPTS 16384       // 16*32*32
#define KK   8192
#define Z_OUT 4194304    // NPTS*CC
// d_out: [0,Z_OUT) z_q_out (BCHW), [Z_OUT,Z_OUT+NPTS) idx as float, [Z_OUT+NPTS] loss
// d_out scratch: zb16 = bf16[16384][256] at slot 0, ebf = bf16[8192][256] at slot
// 2,097,152 -- both dead once k_cand completes; k_final overwrites with z_q BCHW.

// ws layout (floats)
#define WS_ENORM 16448
#define WS_CCNT  24640                // int[16384] candidate counts
#define WS_CIDX  41024                // int[16384][64] candidate k lists
#define CAND_CAP 64
#define LCAP     32                   // per-eighth per-n LDS list capacity (packed 4B)
#define MARGIN   4.0e-4f              // > 2*eps_bf16 + d-quantum + enorm spread
#define BF_GUARD 4.0e-5f              // covers bf16 packing of stored dots

typedef short v8s __attribute__((ext_vector_type(8)));
typedef float v4f __attribute__((ext_vector_type(4)));

__device__ __forceinline__ void gl_lds16(const void* g, void* l) {
    __builtin_amdgcn_global_load_lds((const __attribute__((address_space(1))) void*)g,
                                     (__attribute__((address_space(3))) void*)l, 16, 0, 0);
}
__device__ __forceinline__ unsigned short f2bf(float f) {   // RNE, finite inputs
    unsigned int u = __float_as_uint(f);
    return (unsigned short)((u + 0x7FFFu + ((u >> 16) & 1u)) >> 16);
}
__device__ __forceinline__ float bf2f(unsigned short s) {
    return __uint_as_float(((unsigned)s) << 16);
}

// ---------------- P0 (fused prep): emb->ebf+enorm, z->zb16, zero accumulators -------
// 3072 blocks x 256 thr. Blocks [0,2048): emb fp32 -> ebf bf16 + enorm (4 rows/blk,
// wave/row); blocks [0,64) additionally zero candCnt; block 0 zeros lossAcc+doneCnt.
// Blocks [2048,3072): z BCHW fp32 -> zb16[n][c] bf16 (grid dim3(16,4,16) linearized
// as b2 = bid-2048: x=b2&15, y=(b2>>4)&3, b=b2>>6).
__global__ void k_prep(const float* __restrict__ z, const float* __restrict__ emb,
                       unsigned short* __restrict__ zb16, unsigned short* __restrict__ ebf,
                       float* __restrict__ enorm, float* __restrict__ lossAcc,
                       int* __restrict__ doneCnt, int* __restrict__ candCnt) {
    const int bid = blockIdx.x;
    const int tid = threadIdx.x;
    if (bid < 2048) {
        const int w = tid >> 6, lane = tid & 63;
        const int k = bid * 4 + w;
        const int i = k * CC + lane * 4;
        float4 v = *(const float4*)(emb + i);
        *(ushort4*)(ebf + i) = make_ushort4(f2bf(v.x), f2bf(v.y), f2bf(v.z), f2bf(v.w));
        float s = v.x * v.x + v.y * v.y + v.z * v.z + v.w * v.w;
        for (int off = 32; off > 0; off >>= 1) s += __shfl_down(s, off);
        if (lane == 0) enorm[k] = s;
        if (bid < 64) candCnt[bid * 256 + tid] = 0;
        if (bid == 0 && tid == 0) { lossAcc[0] = 0.0f; doneCnt[0] = 0; }
    } else {
        __shared__ float ts[64][65];
        const int b2 = bid - 2048;
        const int hw0 = (b2 & 15) * 64, c0 = ((b2 >> 4) & 3) * 64, b = b2 >> 6;
#pragma unroll
        for (int p = 0; p < 4; ++p) {
            int u = p * 256 + tid;
            int ci = u >> 4, j4 = (u & 15) << 2;
            float4 v = *(const float4*)(z + (size_t)b * 262144 + (size_t)(c0 + ci) * 1024 + hw0 + j4);
            ts[ci][j4 + 0] = v.x; ts[ci][j4 + 1] = v.y; ts[ci][j4 + 2] = v.z; ts[ci][j4 + 3] = v.w;
        }
        __syncthreads();
#pragma unroll
        for (int p = 0; p < 4; ++p) {
            int u = p * 256 + tid;
            int hj = u >> 4, i4 = (u & 15) << 2;
            ushort4 o = make_ushort4(f2bf(ts[i4 + 0][hj]), f2bf(ts[i4 + 1][hj]),
                                     f2bf(ts[i4 + 2][hj]), f2bf(ts[i4 + 3][hj]));
            *(ushort4*)(zb16 + (size_t)(b * 1024 + hw0 + hj) * 256 + c0 + i4) = o;
        }
    }
}

// ---------------- Phase 1: m97-style staged MFMA candidate generation ---------------
// STRUCTURAL FIX (r12 falsified occupancy; r8 latency-depth; r10 A-BW -- invariant
// ~18% MfmaUtil came from per-wave global->VGPR prefetch exposing L2/L3 latency in
// every wave's stream: measured ~977 cyc/cc-step vs 78 cyc MFMA). This round uses
// the m97-verified ladder pattern (517->874 TF step): BOTH operands staged to LDS
// via global_load_lds (DMA, no VGPR round-trip), double-buffered, ONE barrier per
// step amortizing the vmcnt drain across all waves; per wave per step 8 ds_read_b128
// + 16 MFMA (m97's exact ratio).
// Grid dim3(8,128): block = 128n x 1024k (k-eighth). 256 thr = 4 waves; wave (wr,wc)
// owns the 64k x 64n quadrant of each 128x128 dot tile. 64 steps = 8 ktiles x 8
// c-chunks; acc accumulates over c, epilogue per ktile (8 per block):
// barrier-converged runmax merge (DETERMINISTIC thresholds -- no atomicMax, no
// staleness; r11's overflow came from racing stale runmax) then push (k,dot) packed
// (ushort k, bf16 dot) to LDS lists. Block-end: filter vs block's TRUE eighth-max
// - MARGIN - BF_GUARD, push survivors to global candCnt/candI atomics.
// Soundness: dot(k*) >= M_global - MARGIN >= M_eighth - MARGIN, so the union over
// the 8 k-eighth blocks contains the argmin; bf16 pack covered by BF_GUARD
// (superset-only); any overflow -> candCnt+=KK -> exact full-scan fallback.
// LDS 50 KB -> 3 blocks/CU; regs ~120 < 170 cap. Spill tripwire: WRITE_SIZE.
// mfma_f32_16x16x32_bf16: A[m=lane&15][c=(lane>>4)*8+j]; B[c][n=lane&15];
// D: col(n)=lane&15, row(k)=(lane>>4)*4+reg.
__global__ __launch_bounds__(256, 3)
void k_cand(const unsigned short* __restrict__ zb16, const unsigned short* __restrict__ ebf,
            int* __restrict__ candCnt, int* __restrict__ candI) {
    __shared__ short          Es[2][8][512];    // 16 KB [buf][ktfrag][lane*8] e 128k x 32c
    __shared__ short          Zs[2][8][512];    // 16 KB [buf][ntfrag][lane*8] z 128n x 32c
    __shared__ float          runmax[128];
    __shared__ float          wavemax[4][64];
    __shared__ int            cnt[128];
    __shared__ unsigned short lstK[128][LCAP];  // 8 KB (k < 8192 fits ushort)
    __shared__ unsigned short lstD[128][LCAP];  // 8 KB (dot packed bf16)

    const int tid  = threadIdx.x;
    const int lane = tid & 63;
    const int w    = tid >> 6;              // 0..3
    const int wr   = w >> 1, wc = w & 1;    // wave's k-half / n-half of 128x128 tile
    const int kq   = blockIdx.x;            // k-eighth: k in [kq*1024, +1024)
    const int nb   = blockIdx.y << 7;       // 128-n tile base
    const int m16  = lane & 15, q = lane >> 4;

    if (tid < 128) { runmax[tid] = -__builtin_inff(); cnt[tid] = 0; }

    // stage step t (= ktile*8 + cc) into buf = t&1: 8 e-frags + 8 z-frags, 2+2/wave.
    // Fragment order: lane's 16B IS its MFMA operand fragment (r4-verified layout);
    // gl_lds dest = uniform base + lane*16, global src per-lane.
    auto stage = [&](int t) {
        const int kt8 = t >> 3, cc = t & 7, buf = t & 1;
        const int kbase = (kq << 10) + (kt8 << 7);
#pragma unroll
        for (int p = 0; p < 2; ++p) {
            const int f = w * 2 + p;       // fragment 0..7, wave-uniform
            const unsigned short* ge = ebf  + (size_t)(kbase + f * 16 + m16) * 256 + cc * 32 + q * 8;
            gl_lds16(ge, &Es[buf][f][lane * 8]);
            const unsigned short* gz = zb16 + (size_t)(nb    + f * 16 + m16) * 256 + cc * 32 + q * 8;
            gl_lds16(gz, &Zs[buf][f][lane * 8]);
        }
    };

    stage(0);

    v4f acc[16];
#pragma unroll
    for (int i = 0; i < 16; ++i) acc[i] = (v4f){0.f, 0.f, 0.f, 0.f};

#pragma unroll 1
    for (int t = 0; t < 64; ++t) {
        __syncthreads();                    // buf(t) staged; barrier drains vmcnt once
        if (t + 1 < 64) stage(t + 1);       // prefetch next step into other buf
        const int buf = t & 1;
        v8s a[4], b[4];
#pragma unroll
        for (int i = 0; i < 4; ++i) a[i] = *(const v8s*)&Es[buf][wr * 4 + i][lane * 8];
#pragma unroll
        for (int i = 0; i < 4; ++i) b[i] = *(const v8s*)&Zs[buf][wc * 4 + i][lane * 8];
#pragma unroll
        for (int kt = 0; kt < 4; ++kt)
#pragma unroll
            for (int nt = 0; nt < 4; ++nt)
                acc[kt * 4 + nt] = __builtin_amdgcn_mfma_f32_16x16x32_bf16(
                    a[kt], b[nt], acc[kt * 4 + nt], 0, 0, 0);

        if ((t & 7) == 7) {                 // ktile complete (full c=256): epilogue
            const int kbase = (kq << 10) + ((t >> 3) << 7);
            // per-wave column max over its 64 k (reduce kt,r locally, then q via xor)
#pragma unroll
            for (int nt = 0; nt < 4; ++nt) {
                float m = acc[nt][0];
#pragma unroll
                for (int kt = 0; kt < 4; ++kt)
#pragma unroll
                    for (int r = 0; r < 4; ++r) m = fmaxf(m, acc[kt * 4 + nt][r]);
                m = fmaxf(m, __shfl_xor(m, 16));
                m = fmaxf(m, __shfl_xor(m, 32));
                if (lane < 16) wavemax[w][nt * 16 + lane] = m;
            }
            __syncthreads();
            if (tid < 128) {                // merge the two k-half waves per n-column
                const int half = tid >> 6, idx = tid & 63;
                float r2 = fmaxf(wavemax[half][idx], wavemax[2 + half][idx]);
                runmax[tid] = fmaxf(runmax[tid], r2);
            }
            __syncthreads();
            // push vs CONVERGED block-runmax (deterministic, no staleness)
#pragma unroll
            for (int nt = 0; nt < 4; ++nt) {
                const int nl = wc * 64 + nt * 16 + m16;
                const float thr = runmax[nl] - MARGIN;
#pragma unroll
                for (int kt = 0; kt < 4; ++kt)
#pragma unroll
                    for (int r = 0; r < 4; ++r) {
                        if (acc[kt * 4 + nt][r] >= thr) {
                            int k = kbase + wr * 64 + (kt << 4) + q * 4 + r;
                            int pos = atomicAdd(&cnt[nl], 1);
                            if (pos < LCAP) {
                                lstK[nl][pos] = (unsigned short)k;
                                lstD[nl][pos] = f2bf(acc[kt * 4 + nt][r]);
                            }
                        }
                    }
            }
#pragma unroll
            for (int i = 0; i < 16; ++i) acc[i] = (v4f){0.f, 0.f, 0.f, 0.f};
        }
    }

    __syncthreads();   // runmax = TRUE max of this block's k-eighth per n
    if (tid < 128) {
        const int n = nb + tid;
        const int c = cnt[tid];
        if (c > LCAP) {
            atomicAdd(&candCnt[n], KK);    // overflow -> force full-scan fallback
        } else {
            // widened by BF_GUARD: stored dots are bf16-rounded (abs err <= ~1.4e-5)
            const float thr = runmax[tid] - MARGIN - BF_GUARD;
            for (int i = 0; i < c; ++i) {
                if (bf2f(lstD[tid][i]) >= thr) {
                    int pos = atomicAdd(&candCnt[n], 1);
                    if (pos < CAND_CAP) candI[(size_t)n * CAND_CAP + pos] = (int)lstK[tid][i];
                }
            }
        }
    }
}

// ---------------- Phase 2 (fused): stage + rescore + gather + loss (+finalize) ------
// 512 blocks x 256 thr (4 waves). Block = 32 consecutive hw (b = bid>>5, hw0 =
// (bid&31)*32); LDS 33.4 KB -> 4 blocks/CU. Rescore: wave per n (8 per wave), lane l
// holds zl[j][4l..4l+3]; zn butterfly shifts all d of an n equally -> argmin/
// tie-break invariant. d = (zn + enorm[k]) - (p+p); ties -> min k (order-invariant,
// robust to the nondeterministic cross-block candidate order). Loss finalized by the
// LAST block via doneCnt (device-scope atomics; __threadfence orders each block's
// lossAcc add before its doneCnt increment; no spin-wait anywhere -> no deadlock).
__global__ __launch_bounds__(256)
void k_final(const float* __restrict__ z, const float* __restrict__ emb,
             const float* __restrict__ enorm, const int* __restrict__ candCnt,
             const int* __restrict__ candI, float* __restrict__ out,
             float* __restrict__ idxf, float* __restrict__ lossAcc,
             int* __restrict__ doneCnt, float* __restrict__ outLoss) {
    __shared__ float zl[32][261];     // [hw][c], 33.4 KB
    __shared__ int   kis[32];
    __shared__ float red[256];
    const int bid = blockIdx.x;
    const int b = bid >> 5, hw0 = (bid & 31) << 5;
    const int tid = threadIdx.x;
    const int lane = tid & 63, w = tid >> 6;

    // stage: read float4 along hw (coalesced), transpose into zl[hw][c]
#pragma unroll
    for (int p = 0; p < 8; ++p) {
        const int u = p * 256 + tid;
        const int c = u >> 3, j4 = (u & 7) << 2;
        float4 v = *(const float4*)(z + (size_t)b * 262144 + (size_t)c * 1024 + hw0 + j4);
        zl[j4 + 0][c] = v.x; zl[j4 + 1][c] = v.y; zl[j4 + 2][c] = v.z; zl[j4 + 3][c] = v.w;
    }
    __syncthreads();

    // rescore: wave per n, 8 n per wave
#pragma unroll 1
    for (int rr = 0; rr < 8; ++rr) {
        const int j = w * 8 + rr;
        const int n = b * 1024 + hw0 + j;
        const float4 zv = *(const float4*)&zl[j][lane * 4];
        float zn = zv.x * zv.x;
        zn = fmaf(zv.y, zv.y, zn); zn = fmaf(zv.z, zv.z, zn); zn = fmaf(zv.w, zv.w, zn);
#pragma unroll
        for (int off = 1; off < 64; off <<= 1) zn += __shfl_xor(zn, off);
        const int cnt = candCnt[n];
        float bd = __builtin_inff();
        int   bk = 0x7fffffff;
        if (cnt <= CAND_CAP) {
#pragma unroll 1
            for (int i = 0; i < cnt; ++i) {
                const int k = candI[(size_t)n * CAND_CAP + i];
                const float4 ev = *(const float4*)(emb + (size_t)k * CC + lane * 4);
                float p = zv.x * ev.x;
                p = fmaf(zv.y, ev.y, p);
                p = fmaf(zv.z, ev.z, p);
                p = fmaf(zv.w, ev.w, p);
#pragma unroll
                for (int off = 1; off < 64; off <<= 1) p += __shfl_xor(p, off);
                const float d = (zn + enorm[k]) - (p + p);
                if (d < bd || (d == bd && k < bk)) { bd = d; bk = k; }
            }
        } else {
            // overflow fallback: exact full scan, ascending k keeps min-k
#pragma unroll 1
            for (int k = 0; k < KK; ++k) {
                const float4 ev = *(const float4*)(emb + (size_t)k * CC + lane * 4);
                float p = zv.x * ev.x;
                p = fmaf(zv.y, ev.y, p);
                p = fmaf(zv.z, ev.z, p);
                p = fmaf(zv.w, ev.w, p);
#pragma unroll
                for (int off = 1; off < 64; off <<= 1) p += __shfl_xor(p, off);
                const float d = (zn + enorm[k]) - (p + p);
                if (d < bd) { bd = d; bk = k; }
            }
        }
        if (lane == 0) { idxf[n] = (float)bk; kis[j] = bk; }
    }
    __syncthreads();

    // gather z_q (BCHW, coalesced along hw) + loss partials from the LDS tile
    const int j  = tid & 31;          // hw within tile
    const int cg = tid >> 5;          // c-group of 32
    const int ki0 = kis[j];
    const float* ep = emb + (size_t)ki0 * CC;
    float ls = 0.0f;
#pragma unroll 4
    for (int c = cg * 32; c < cg * 32 + 32; ++c) {
        float e  = ep[c];
        float zv = zl[j][c];
        out[(size_t)b * 262144 + (size_t)c * 1024 + hw0 + j] = e;
        float df = e - zv;
        ls = fmaf(df, df, ls);
    }
    red[tid] = ls;
    __syncthreads();
    for (int s2 = 128; s2 > 0; s2 >>= 1) {
        if (tid < s2) red[tid] += red[tid + s2];
        __syncthreads();
    }
    if (tid == 0) {
        atomicAdd(lossAcc, red[0]);
        __threadfence();                              // order lossAcc add before counter
        int old = atomicAdd(doneCnt, 1);
        if (old == (int)gridDim.x - 1) {              // last block finalizes loss
            float tot = atomicAdd(lossAcc, 0.0f);     // coherent read after all adds
            float m = tot * (1.0f / 4194304.0f);
            outLoss[0] = m + 0.25f * m;
        }
    }
}

extern "C" void kernel_launch(void* const* d_in, const int* in_sizes, int n_in,
                              void* d_out, int out_size, void* d_ws, size_t ws_size,
                              hipStream_t stream) {
    const float* z   = (const float*)d_in[0];
    const float* emb = (const float*)d_in[1];
    float* outf = (float*)d_out;
    float* wsf  = (float*)d_ws;

    float* lossAcc = wsf;
    int*   doneCnt = (int*)(wsf + 1);
    float* enorm   = wsf + WS_ENORM;
    int*   candCnt = (int*)(wsf + WS_CCNT);
    int*   candI   = (int*)(wsf + WS_CIDX);

    // d_out z_q region doubles as scratch: bf16 zb16/ebf until k_cand completes,
    // then k_final overwrites it with z_q.
    unsigned short* zb16 = (unsigned short*)outf;                  // 8 MB
    unsigned short* ebf  = (unsigned short*)(outf + 2097152);      // 4 MB

    k_prep<<<3072, 256, 0, stream>>>(z, emb, zb16, ebf, enorm, lossAcc, doneCnt, candCnt);
    k_cand<<<dim3(8, 128), 256, 0, stream>>>(zb16, ebf, candCnt, candI);
    k_final<<<512, 256, 0, stream>>>(z, emb, enorm, candCnt, candI,
                                     outf, outf + Z_OUT, lossAcc, doneCnt,
                                     outf + Z_OUT + NPTS);
}

// Round 14
// 267.060 us; speedup vs baseline: 14.4366x; 14.4366x over previous
//
#include <hip/hip_runtime.h>
#include <math.h>

// Problem constants
#define NB   16
#define CC   256
#define NPTS 16384       // 16*32*32
#define KK   8192
#define Z_OUT 4194304    // NPTS*CC
// d_out: [0,Z_OUT) z_q_out (BCHW), [Z_OUT,Z_OUT+NPTS) idx as float, [Z_OUT+NPTS] loss
// d_out scratch: zb16 = bf16[16384][256] at slot 0, ebf = bf16[8192][256] at slot
// 2,097,152 -- both dead once k_cand completes; k_final overwrites with z_q BCHW.

// ws layout (floats)
#define WS_ENORM 16448
#define WS_CCNT  24640                // int[16384] candidate counts
#define WS_CIDX  41024                // int[16384][64] candidate k lists
#define CAND_CAP 64
#define LCAP     96                   // pre-filter per-n LDS list capacity
#define MARGIN   4.0e-4f              // > 2*eps_bf16 + d-quantum + enorm spread

typedef short v8s __attribute__((ext_vector_type(8)));
typedef float v4f __attribute__((ext_vector_type(4)));

__device__ __forceinline__ void gl_lds16(const void* g, void* l) {
    __builtin_amdgcn_global_load_lds((const __attribute__((address_space(1))) void*)g,
                                     (__attribute__((address_space(3))) void*)l, 16, 0, 0);
}
__device__ __forceinline__ unsigned short f2bf(float f) {   // RNE, finite inputs
    unsigned int u = __float_as_uint(f);
    return (unsigned short)((u + 0x7FFFu + ((u >> 16) & 1u)) >> 16);
}
// monotone float<->uint encoding for atomicMax on floats of any sign
__device__ __forceinline__ unsigned fenc(float f) {
    unsigned u = __float_as_uint(f);
    return (u & 0x80000000u) ? ~u : (u | 0x80000000u);
}
__device__ __forceinline__ float fdec(unsigned m) {
    unsigned u = (m & 0x80000000u) ? (m & 0x7fffffffu) : ~m;
    return __uint_as_float(u);
}

// ---------------- P0: z BCHW fp32 -> zb16[n][c] bf16 (transpose+cast) ----------------
__global__ void k_prep_z(const float* __restrict__ z, unsigned short* __restrict__ zb16) {
    __shared__ float ts[64][65];
    const int hw0 = blockIdx.x * 64, c0 = blockIdx.y * 64, b = blockIdx.z;
    const int tid = threadIdx.x;
#pragma unroll
    for (int p = 0; p < 4; ++p) {
        int u = p * 256 + tid;
        int ci = u >> 4, j4 = (u & 15) << 2;
        float4 v = *(const float4*)(z + (size_t)b * 262144 + (size_t)(c0 + ci) * 1024 + hw0 + j4);
        ts[ci][j4 + 0] = v.x; ts[ci][j4 + 1] = v.y; ts[ci][j4 + 2] = v.z; ts[ci][j4 + 3] = v.w;
    }
    __syncthreads();
#pragma unroll
    for (int p = 0; p < 4; ++p) {
        int u = p * 256 + tid;
        int hj = u >> 4, i4 = (u & 15) << 2;
        ushort4 o = make_ushort4(f2bf(ts[i4 + 0][hj]), f2bf(ts[i4 + 1][hj]),
                                 f2bf(ts[i4 + 2][hj]), f2bf(ts[i4 + 3][hj]));
        *(ushort4*)(zb16 + (size_t)(b * 1024 + hw0 + hj) * 256 + c0 + i4) = o;
    }
}

// ---------------- P1: emb fp32 -> ebf[k][c] bf16, fused enorm + accumulator zeroing --
__global__ void k_prep_e(const float* __restrict__ emb, unsigned short* __restrict__ ebf,
                         float* __restrict__ enorm, float* __restrict__ lossAcc,
                         int* __restrict__ doneCnt) {
    const int w = threadIdx.x >> 6, lane = threadIdx.x & 63;
    const int k = blockIdx.x * 4 + w;
    const int i = k * CC + lane * 4;
    float4 v = *(const float4*)(emb + i);
    *(ushort4*)(ebf + i) = make_ushort4(f2bf(v.x), f2bf(v.y), f2bf(v.z), f2bf(v.w));
    float s = v.x * v.x + v.y * v.y + v.z * v.z + v.w * v.w;
    for (int off = 32; off > 0; off >>= 1) s += __shfl_down(s, off);
    if (lane == 0) enorm[k] = s;
    if (blockIdx.x == 0 && threadIdx.x == 0) { lossAcc[0] = 0.0f; doneCnt[0] = 0; }
}

// ---------------- Phase 1: single-sweep MFMA candidate generation -------------------
// r8-verified structure (145 us): r6 base + depth-3 A-prefetch ring. 256 blocks x
// 512 thr (8 waves, 2/SIMD, 256-reg budget). Block = 64 n; B z-tile staged ONCE in
// LDS (32 KB, shared by all 8 waves -> block reads ebf exactly once = 4 MB). Wave w
// sweeps chunks ci = s*8 + w (64 k each), strided sliding L2 window.
// A ring: 4 buffers aR[4], slot = cc&3 (8-step unrolled loop, 8%4==0 -> static
// indices every s). At step cc we issue the load for step cc+3 (~234 cy of MFMA
// ahead); per-register counted vmcnt keeps 3 loads in flight, and the s-epilogue
// VALU work overlaps the 3 cross-boundary prefetches. B ping-pong depth-1 from LDS.
// Candidate semantics (verified r4-r8): progressive threshold max(shared runmax,
// own chunk max) - MARGIN (superset-safe under staleness), (k,dot) -> LDS lists,
// exact final filter vs TRUE block-global max, overflow -> full-scan fallback.
// mfma_f32_16x16x32_bf16: A[m=lane&15][c=(lane>>4)*8+j]; B[c][n=lane&15];
// D: col(n)=lane&15, row(k)=(lane>>4)*4+reg.
__global__ __launch_bounds__(512, 2)
void k_cand(const unsigned short* __restrict__ zb16, const unsigned short* __restrict__ ebf,
            int* __restrict__ candCnt, int* __restrict__ candI) {
    __shared__ short    Bs[8][4][512];      // 32 KB  [cchunk][ntile][lane*8]
    __shared__ unsigned runmaxU[64];        // ordered-uint running max per n
    __shared__ int      cnt[64];
    __shared__ int      lstK[64][LCAP];     // 24 KB
    __shared__ float    lstD[64][LCAP];     // 24 KB

    const int tid  = threadIdx.x;
    const int lane = tid & 63;
    const int w    = tid >> 6;              // 0..7
    const int nb   = blockIdx.x << 6;
    const int m16  = lane & 15, q = lane >> 4;

    if (tid < 64) { runmaxU[tid] = 0x007FFFFFu; /* fenc(-inf) */ cnt[tid] = 0; }

    // stage B-tile once: 32 (cc,nt) fragments x 64 lanes x 16B; 4 per wave
#pragma unroll
    for (int p = 0; p < 4; ++p) {
        const int g8 = p * 8 + w;          // 0..31, wave-uniform
        const int cc = g8 >> 2, nt = g8 & 3;
        const unsigned short* g = zb16 + (size_t)(nb + nt * 16 + m16) * 256 + cc * 32 + q * 8;
        gl_lds16(g, &Bs[cc][nt][lane * 8]);
    }

    auto loadA = [&](v8s (&a)[4], int kbr, int cc) {
#pragma unroll
        for (int kt = 0; kt < 4; ++kt)
            a[kt] = *(const v8s*)(ebf + (size_t)(kbr + (kt << 4) + m16) * 256 + (cc << 5) + q * 8);
    };
    auto loadB = [&](v8s (&b)[4], int cc) {
#pragma unroll
        for (int nt = 0; nt < 4; ++nt) b[nt] = *(const v8s*)&Bs[cc][nt][lane * 8];
    };

    v8s aR[4][4];            // A ring (static indices only -- cc fully unrolled)
    v8s bP[4], bN[4];

    // prologue: seed ring with (s=0, cc=0,1,2); registers only, safe pre-barrier
    const int kb0 = w << 6;                // s=0 -> ci=w
    loadA(aR[0], kb0, 0);
    loadA(aR[1], kb0, 1);
    loadA(aR[2], kb0, 2);
    __syncthreads();       // Bs staged + runmaxU/cnt init visible (drains vmcnt once)
    loadB(bP, 0);

#pragma unroll 1
    for (int s = 0; s < 16; ++s) {
        const int kb  = ((s << 3) + w) << 6;           // this wave's chunk (64 k)
        const int kbn = (s < 15) ? kb + 512 : kb;      // next s's chunk (ci+8)
        v4f acc[16];
#pragma unroll
        for (int i = 0; i < 16; ++i) acc[i] = (v4f){0.f, 0.f, 0.f, 0.f};

#pragma unroll
        for (int cc = 0; cc < 8; ++cc) {
            // B ping-pong: prefetch next cc (B(cc) is the same LDS data every s,
            // so (cc+1)&7 at cc=7 pre-loads next-s cc=0).
            if ((cc & 1) == 0) loadB(bN, (cc + 1) & 7);
            else               loadB(bP, (cc + 1) & 7);
            // A ring: issue load for step cc+3 into slot (cc+3)&3
            {
                const int tcc = cc + 3;
                if (tcc < 8) loadA(aR[tcc & 3], kb,  tcc);
                else         loadA(aR[tcc & 3], kbn, tcc - 8);
            }
            // MFMA with slot cc&3 (loaded 3 steps ago) and the cc-parity B buffer
#pragma unroll
            for (int kt = 0; kt < 4; ++kt)
#pragma unroll
                for (int nt = 0; nt < 4; ++nt)
                    acc[kt * 4 + nt] = __builtin_amdgcn_mfma_f32_16x16x32_bf16(
                        aR[cc & 3][kt], ((cc & 1) ? bN[nt] : bP[nt]),
                        acc[kt * 4 + nt], 0, 0, 0);
        }

        // chunk epilogue: own-chunk max per n-column, merge into shared runmax, push.
        // (3 A-loads for next s are in flight across this VALU section.)
        float mx[4];
#pragma unroll
        for (int nt = 0; nt < 4; ++nt) {
            float m = acc[0 * 4 + nt][0];
#pragma unroll
            for (int kt = 0; kt < 4; ++kt)
#pragma unroll
                for (int r = 0; r < 4; ++r) m = fmaxf(m, acc[kt * 4 + nt][r]);
            m = fmaxf(m, __shfl_xor(m, 16));
            m = fmaxf(m, __shfl_xor(m, 32));
            mx[nt] = m;                     // all lanes: chunk max of column nt*16+m16
            if (lane < 16) atomicMax(&runmaxU[nt * 16 + lane], fenc(m));
        }
#pragma unroll
        for (int nt = 0; nt < 4; ++nt) {
            const int nl = nt * 16 + m16;
            const float thr = fmaxf(fdec(runmaxU[nl]), mx[nt]) - MARGIN;
#pragma unroll
            for (int kt = 0; kt < 4; ++kt)
#pragma unroll
                for (int r = 0; r < 4; ++r) {
                    if (acc[kt * 4 + nt][r] >= thr) {
                        int k = kb + (kt << 4) + q * 4 + r;
                        int pos = atomicAdd(&cnt[nl], 1);
                        if (pos < LCAP) { lstK[nl][pos] = k; lstD[nl][pos] = acc[kt * 4 + nt][r]; }
                    }
                }
        }
        if (s == 3 || s == 9) __syncthreads();   // bound cross-wave staleness
    }

    __syncthreads();   // all pushes + atomicMax done; runmaxU now TRUE global max per n
    if (tid < 64) {
        const int n = nb + tid;
        const int c = cnt[tid];
        if (c > LCAP) {
            candCnt[n] = KK;               // overflow -> exact full-scan fallback
        } else {
            const float thr = fdec(runmaxU[tid]) - MARGIN;
            int kept = 0;
            for (int i = 0; i < c; ++i) {
                if (lstD[tid][i] >= thr) {
                    if (kept < CAND_CAP) candI[(size_t)n * CAND_CAP + kept] = lstK[tid][i];
                    ++kept;
                }
            }
            candCnt[n] = (kept > CAND_CAP) ? KK : kept;
        }
    }
}

// ---------------- Phase 2 (fused): stage + rescore + gather + loss (+finalize) ------
// r8-verified structure. 512 blocks x 256 thr (4 waves). Block = 32 consecutive hw
// (b = bid>>5, hw0 = (bid&31)*32); LDS 33.4 KB -> 4 blocks/CU. Rescore: wave per n
// (8 per wave), lane l holds zl[j][4l..4l+3]; zn butterfly shifts all d of an n
// equally -> argmin/tie-break invariant. d = (zn + enorm[k]) - (p+p); ties -> min k.
// NEW vs r8 (only change this round, r10/r12-verified pattern): loss finalized by
// the LAST block via doneCnt (device-scope atomics; __threadfence orders each
// block's lossAcc add before its doneCnt increment; no spin-wait -> no deadlock).
// Removes the k_loss launch.
__global__ __launch_bounds__(256)
void k_final(const float* __restrict__ z, const float* __restrict__ emb,
             const float* __restrict__ enorm, const int* __restrict__ candCnt,
             const int* __restrict__ candI, float* __restrict__ out,
             float* __restrict__ idxf, float* __restrict__ lossAcc,
             int* __restrict__ doneCnt, float* __restrict__ outLoss) {
    __shared__ float zl[32][261];     // [hw][c], 33.4 KB
    __shared__ int   kis[32];
    __shared__ float red[256];
    const int bid = blockIdx.x;
    const int b = bid >> 5, hw0 = (bid & 31) << 5;
    const int tid = threadIdx.x;
    const int lane = tid & 63, w = tid >> 6;

    // stage: read float4 along hw (coalesced), transpose into zl[hw][c]
#pragma unroll
    for (int p = 0; p < 8; ++p) {
        const int u = p * 256 + tid;
        const int c = u >> 3, j4 = (u & 7) << 2;
        float4 v = *(const float4*)(z + (size_t)b * 262144 + (size_t)c * 1024 + hw0 + j4);
        zl[j4 + 0][c] = v.x; zl[j4 + 1][c] = v.y; zl[j4 + 2][c] = v.z; zl[j4 + 3][c] = v.w;
    }
    __syncthreads();

    // rescore: wave per n, 8 n per wave
#pragma unroll 1
    for (int rr = 0; rr < 8; ++rr) {
        const int j = w * 8 + rr;
        const int n = b * 1024 + hw0 + j;
        const float4 zv = *(const float4*)&zl[j][lane * 4];
        float zn = zv.x * zv.x;
        zn = fmaf(zv.y, zv.y, zn); zn = fmaf(zv.z, zv.z, zn); zn = fmaf(zv.w, zv.w, zn);
#pragma unroll
        for (int off = 1; off < 64; off <<= 1) zn += __shfl_xor(zn, off);
        const int cnt = candCnt[n];
        float bd = __builtin_inff();
        int   bk = 0x7fffffff;
        if (cnt <= CAND_CAP) {
#pragma unroll 1
            for (int i = 0; i < cnt; ++i) {
                const int k = candI[(size_t)n * CAND_CAP + i];
                const float4 ev = *(const float4*)(emb + (size_t)k * CC + lane * 4);
                float p = zv.x * ev.x;
                p = fmaf(zv.y, ev.y, p);
                p = fmaf(zv.z, ev.z, p);
                p = fmaf(zv.w, ev.w, p);
#pragma unroll
                for (int off = 1; off < 64; off <<= 1) p += __shfl_xor(p, off);
                const float d = (zn + enorm[k]) - (p + p);
                if (d < bd || (d == bd && k < bk)) { bd = d; bk = k; }
            }
        } else {
            // overflow fallback: exact full scan, ascending k keeps min-k
#pragma unroll 1
            for (int k = 0; k < KK; ++k) {
                const float4 ev = *(const float4*)(emb + (size_t)k * CC + lane * 4);
                float p = zv.x * ev.x;
                p = fmaf(zv.y, ev.y, p);
                p = fmaf(zv.z, ev.z, p);
                p = fmaf(zv.w, ev.w, p);
#pragma unroll
                for (int off = 1; off < 64; off <<= 1) p += __shfl_xor(p, off);
                const float d = (zn + enorm[k]) - (p + p);
                if (d < bd) { bd = d; bk = k; }
            }
        }
        if (lane == 0) { idxf[n] = (float)bk; kis[j] = bk; }
    }
    __syncthreads();

    // gather z_q (BCHW, coalesced along hw) + loss partials from the LDS tile
    const int j  = tid & 31;          // hw within tile
    const int cg = tid >> 5;          // c-group of 32
    const int ki0 = kis[j];
    const float* ep = emb + (size_t)ki0 * CC;
    float ls = 0.0f;
#pragma unroll 4
    for (int c = cg * 32; c < cg * 32 + 32; ++c) {
        float e  = ep[c];
        float zv = zl[j][c];
        out[(size_t)b * 262144 + (size_t)c * 1024 + hw0 + j] = e;
        float df = e - zv;
        ls = fmaf(df, df, ls);
    }
    red[tid] = ls;
    __syncthreads();
    for (int s2 = 128; s2 > 0; s2 >>= 1) {
        if (tid < s2) red[tid] += red[tid + s2];
        __syncthreads();
    }
    if (tid == 0) {
        atomicAdd(lossAcc, red[0]);
        __threadfence();                              // order lossAcc add before counter
        int old = atomicAdd(doneCnt, 1);
        if (old == (int)gridDim.x - 1) {              // last block finalizes loss
            float tot = atomicAdd(lossAcc, 0.0f);     // coherent read after all adds
            float m = tot * (1.0f / 4194304.0f);
            outLoss[0] = m + 0.25f * m;
        }
    }
}

extern "C" void kernel_launch(void* const* d_in, const int* in_sizes, int n_in,
                              void* d_out, int out_size, void* d_ws, size_t ws_size,
                              hipStream_t stream) {
    const float* z   = (const float*)d_in[0];
    const float* emb = (const float*)d_in[1];
    float* outf = (float*)d_out;
    float* wsf  = (float*)d_ws;

    float* lossAcc = wsf;
    int*   doneCnt = (int*)(wsf + 1);
    float* enorm   = wsf + WS_ENORM;
    int*   candCnt = (int*)(wsf + WS_CCNT);
    int*   candI   = (int*)(wsf + WS_CIDX);

    // d_out z_q region doubles as scratch: bf16 zb16/ebf until k_cand completes,
    // then k_final overwrites it with z_q.
    unsigned short* zb16 = (unsigned short*)outf;                  // 8 MB
    unsigned short* ebf  = (unsigned short*)(outf + 2097152);      // 4 MB

    k_prep_e<<<2048, 256, 0, stream>>>(emb, ebf, enorm, lossAcc, doneCnt);
    k_prep_z<<<dim3(16, 4, 16), 256, 0, stream>>>(z, zb16);
    k_cand<<<256, 512, 0, stream>>>(zb16, ebf, candCnt, candI);
    k_final<<<512, 256, 0, stream>>>(z, emb, enorm, candCnt, candI,
                                     outf, outf + Z_OUT, lossAcc, doneCnt,
                                     outf + Z_OUT + NPTS);
}